// Round 5
// baseline (187.476 us; speedup 1.0000x reference)
//
#include <hip/hip_runtime.h>

// NeuromodulatedAttention — MI355X (gfx950), round 12
//
// ALGEBRA: (1) dopamine/serotonin "mod" is a per-row constant added before the
// per-row mean/std normalization -> cancels exactly (both MLPs are dead code).
// (2) the mean subtraction is a per-row constant inside softmax -> also cancels.
// Effective:  out = softmax( S * istd_row ) @ V,
//   S = Q K^T / sqrt(512),  istd_row = 1/(std(S_row, ddof=1) + 1e-6).
//
// Round-12 delta vs round 11 (179.5us; smpv 50.6us — the counted-vmcnt graft
// REGRESSED vs r10's 40.8 (2 barriers/iter + sched_barrier pins; T3/T4 only pay
// inside a full 8-phase schedule, not as a graft)):
//   * smpv_kernel: revert to r10's one-barrier double-buffered loop, but at
//     2 blocks/CU for TLP latency hiding (the actual fix for "everything low +
//     occupancy 17%"): block = 64q x 128d, 4 waves, LDS ~49KB, grid 512 = 2/CU.
//     exp replication x4 (+~7us overlappable work) buys co-resident-block
//     overlap of every barrier/L2 stall. XCD decode keeps 2 V-slices (1MB)
//     per XCD L2.
//   * qk / prep / stats / fallback: byte-identical to round 10/11.

#define BB 4
#define SS 2048
#define DD 512
#define SCALE 0.044194173824159216f  // 1/sqrt(512)
#define LOG2E 1.4426950408889634f

typedef __bf16 bf16;
typedef _Float16 f16;
typedef bf16 bf16x2 __attribute__((ext_vector_type(2)));
typedef bf16 bf16x4 __attribute__((ext_vector_type(4)));
typedef bf16 bf16x8 __attribute__((ext_vector_type(8)));
typedef f16  f16x8  __attribute__((ext_vector_type(8)));
typedef float f32x16 __attribute__((ext_vector_type(16)));

// async 16B/lane global->LDS; LDS dest = wave-uniform base + lane*16.
__device__ __forceinline__ void gload_lds16(const bf16* g, bf16* l) {
  __builtin_amdgcn_global_load_lds(
      (const __attribute__((address_space(1))) void*)g,
      (__attribute__((address_space(3))) void*)l, 16, 0, 0);
}

// ---------------- K1: prep = cast Q,K (bf16) + transpose V (bf16 [b][d][s]) ----

__global__ void prep_kernel(const float* __restrict__ Q, const float* __restrict__ K,
                            const float* __restrict__ V,
                            bf16* __restrict__ Qb, bf16* __restrict__ Kb,
                            bf16* __restrict__ Vt) {
  __shared__ bf16 tile[64][80];
  const int bx = blockIdx.x;
  const int t = threadIdx.x;
  if (bx < 2048) {
    // cast 8 elems of Q and K per thread
    size_t i = ((size_t)bx * 256 + t) * 8;
    float4 a0 = *(const float4*)(Q + i);
    float4 a1 = *(const float4*)(Q + i + 4);
    bf16x8 qa = { (bf16)a0.x, (bf16)a0.y, (bf16)a0.z, (bf16)a0.w,
                  (bf16)a1.x, (bf16)a1.y, (bf16)a1.z, (bf16)a1.w };
    *(bf16x8*)(Qb + i) = qa;
    float4 b0 = *(const float4*)(K + i);
    float4 b1 = *(const float4*)(K + i + 4);
    bf16x8 ka = { (bf16)b0.x, (bf16)b0.y, (bf16)b0.z, (bf16)b0.w,
                  (bf16)b1.x, (bf16)b1.y, (bf16)b1.z, (bf16)b1.w };
    *(bf16x8*)(Kb + i) = ka;
  } else {
    // V transpose, 64x64 tile
    const int tt = bx - 2048;
    const int s0 = (tt & 31) * 64, d0 = ((tt >> 5) & 7) * 64, b = tt >> 8;
    const int r16 = t >> 4;
    const int c4  = (t & 15) * 4;
#pragma unroll
    for (int i = 0; i < 4; ++i) {
      int r = i * 16 + r16;
      float4 v = *(const float4*)&V[((size_t)b * SS + s0 + r) * DD + d0 + c4];
      tile[c4 + 0][r] = (bf16)v.x;
      tile[c4 + 1][r] = (bf16)v.y;
      tile[c4 + 2][r] = (bf16)v.z;
      tile[c4 + 3][r] = (bf16)v.w;
    }
    __syncthreads();
    const int dr8 = t >> 3;
    const int sc8 = (t & 7) * 8;
#pragma unroll
    for (int i = 0; i < 2; ++i) {
      int dr = i * 32 + dr8;
      bf16x8 o = *(const bf16x8*)&tile[dr][sc8];
      *(bf16x8*)&Vt[((size_t)b * DD + d0 + dr) * SS + s0 + sc8] = o;
    }
  }
}

// ---------------- K2: QK^T GEMM -> S f16 (unchanged from round 8) ----------------
// grid (16 qt, 8 kt-pair, 4 b), 256 thr (4 waves). Each block: 128q x 256k
// (two 128x128 k-tiles sharing one staged A tile). BK=64 (8 iters).
// Wave (wq=w&1, wn=w>>1) owns the 64x64 quadrant of each 128x128 sub-tile.
// LDS rows 128B, chunk slot s of row r holds global chunk s^(r&7).

__launch_bounds__(256, 2)
__global__ void qk_gemm_kernel(const bf16* __restrict__ Qb, const bf16* __restrict__ Kb,
                               f16* __restrict__ Sp) {
  __shared__ bf16 At[128 * 64];
  __shared__ bf16 Bt[2][128 * 64];

  const int tid  = threadIdx.x;
  const int w    = tid >> 6;
  const int lane = tid & 63;
  const int l31  = lane & 31;
  const int lh   = lane >> 5;
  const int qt = blockIdx.x, kt2 = blockIdx.y, b = blockIdx.z;
  const int q0 = qt * 128, k0 = kt2 * 256;
  const int wq = w & 1, wn = w >> 1;
  const int m0 = wq * 64, n0 = wn * 64;

  const int srow = lane >> 3;          // row within 8-row staging group
  const int sg   = (lane & 7) ^ srow;  // swizzled global chunk index
  const bf16* gA = Qb + ((size_t)b * SS + q0) * DD;
  const bf16* gB = Kb + ((size_t)b * SS + k0) * DD;

  f32x16 acc[2][4];                    // [k-tile half][2*rowhalf + colhalf]
#pragma unroll
  for (int h = 0; h < 2; ++h)
#pragma unroll
    for (int u = 0; u < 4; ++u) acc[h][u] = (f32x16){};

  for (int dc = 0; dc < DD; dc += 64) {
    __syncthreads();
#pragma unroll
    for (int j = 0; j < 4; ++j) {
      int row = w * 32 + j * 8 + srow;
      gload_lds16(gA + (size_t)row * DD + dc + sg * 8, At + (w * 32 + j * 8) * 64);
      gload_lds16(gB + (size_t)row * DD + dc + sg * 8, Bt[0] + (w * 32 + j * 8) * 64);
      gload_lds16(gB + (size_t)(128 + row) * DD + dc + sg * 8,
                  Bt[1] + (w * 32 + j * 8) * 64);
    }
    __syncthreads();
#pragma unroll
    for (int kk = 0; kk < 4; ++kk) {
      int c = kk * 2 + lh;
      int ra0 = m0 + l31, ra1 = m0 + 32 + l31;
      int rb0 = n0 + l31, rb1 = n0 + 32 + l31;
      bf16x8 a0 = *(const bf16x8*)&At[ra0 * 64 + ((c ^ (ra0 & 7)) << 3)];
      bf16x8 a1 = *(const bf16x8*)&At[ra1 * 64 + ((c ^ (ra1 & 7)) << 3)];
#pragma unroll
      for (int h = 0; h < 2; ++h) {
        bf16x8 b0 = *(const bf16x8*)&Bt[h][rb0 * 64 + ((c ^ (rb0 & 7)) << 3)];
        bf16x8 b1 = *(const bf16x8*)&Bt[h][rb1 * 64 + ((c ^ (rb1 & 7)) << 3)];
        acc[h][0] = __builtin_amdgcn_mfma_f32_32x32x16_bf16(a0, b0, acc[h][0], 0, 0, 0);
        acc[h][1] = __builtin_amdgcn_mfma_f32_32x32x16_bf16(a0, b1, acc[h][1], 0, 0, 0);
        acc[h][2] = __builtin_amdgcn_mfma_f32_32x32x16_bf16(a1, b0, acc[h][2], 0, 0, 0);
        acc[h][3] = __builtin_amdgcn_mfma_f32_32x32x16_bf16(a1, b1, acc[h][3], 0, 0, 0);
      }
    }
  }

  int qrow[16];
#pragma unroll
  for (int r = 0; r < 16; ++r) qrow[r] = (r & 3) + 8 * (r >> 2) + 4 * lh;

  // epilogue: pure f16 stores (stats are computed by stats_kernel from S)
#pragma unroll
  for (int h = 0; h < 2; ++h) {
    f16* Sb = Sp + ((size_t)b * SS + q0) * SS + k0 + h * 128 + n0;
#pragma unroll
    for (int i = 0; i < 2; ++i) {
      const f32x16& A0 = acc[h][i * 2 + 0];
      const f32x16& A1 = acc[h][i * 2 + 1];
#pragma unroll
      for (int r = 0; r < 16; ++r) {
        f16* Sr = Sb + (size_t)(m0 + i * 32 + qrow[r]) * SS;
        Sr[l31]      = (f16)(A0[r] * SCALE);
        Sr[32 + l31] = (f16)(A1[r] * SCALE);
      }
    }
  }
}

// ---------------- K3: stats (sum/sumsq -> a1 per row), no exp, no P ----------------
// grid (2048, 4), 256 thr; block = one q-row (2048 f16, 8/thread).

__global__ void stats_kernel(const f16* __restrict__ Sp, float* __restrict__ a1out) {
  __shared__ float redS[4], redQ[4];
  const int row = blockIdx.x, b = blockIdx.y;
  const int tid = threadIdx.x;
  const int lane = tid & 63, w = tid >> 6;
  const size_t base = ((size_t)b * SS + row) * SS;

  f16x8 hv = *(const f16x8*)&Sp[base + tid * 8];
  float s = 0.f, q = 0.f;
#pragma unroll
  for (int j = 0; j < 8; ++j) {
    float v = (float)hv[j];
    s += v;
    q += v * v;
  }
#pragma unroll
  for (int m = 32; m >= 1; m >>= 1) { s += __shfl_xor(s, m); q += __shfl_xor(q, m); }
  if (lane == 0) { redS[w] = s; redQ[w] = q; }
  __syncthreads();
  if (tid == 0) {
    s = redS[0] + redS[1] + redS[2] + redS[3];
    q = redQ[0] + redQ[1] + redQ[2] + redQ[3];
    float mean = s * (1.0f / 2048.0f);
    float var  = (q - 2048.0f * mean * mean) * (1.0f / 2047.0f);
    var = fmaxf(var, 0.0f);
    // p = exp((s-mean)*istd); per-row exp(-mean*istd) cancels in softmax.
    a1out[b * SS + row] = LOG2E / (sqrtf(var) + 1e-6f);
  }
}

// ---------------- K4: fused softmax + PV GEMM -> out (fp32) ----------------
// grid: 512 blocks (bid: dt=bid&3, b=(bid>>2)&3, qt2=bid>>4) = 2 blocks/CU;
// 256 thr (4 waves: wd=w&1 d-tile, wk=w>>1 k-half). Block tile 64q x 128d,
// BK=64 (32 iters), double-buffered LDS (~49KB -> 2 resident, TLP hides the
// per-iter barrier drain that made the 1-block/CU r10/r11 versions stall 85%).
// One __syncthreads per iter (r10 structure, proven). exp map: thread owns
// row er=tid>>2, chunks c=(tid&3) and (tid&3)+4 -> exp2(S*a1) -> bf16 ->
// XOR-swizzled ds_write (same LDS image as a gload of P). den accumulated
// per-thread from the bf16-rounded p; k-halves merged through LDS (Bt reuse).
// XCD decode: bids == x (mod 8) share one dt and 2 b's -> 2 V-slices = 1MB
// per XCD L2.

__launch_bounds__(256, 2)
__global__ void smpv_kernel(const f16* __restrict__ Sp, const bf16* __restrict__ Vt,
                            const float* __restrict__ a1p, float* __restrict__ out) {
  __shared__ bf16 At[2][64 * 64];    // 16 KB
  __shared__ bf16 Bt[2][128 * 64];   // 32 KB (reused as f32[64][128] at end)
  __shared__ float denp[256];
  __shared__ float dinv[64];

  const int tid  = threadIdx.x;
  const int w    = tid >> 6;
  const int lane = tid & 63;
  const int l31  = lane & 31;
  const int lh   = lane >> 5;
  const int wd   = w & 1, wk = w >> 1;
  const int bid  = blockIdx.x;
  const int dt   = bid & 3, b = (bid >> 2) & 3, qt2 = bid >> 4;
  const int q0   = qt2 * 64, d0 = dt * 128;

  // exp staging map: thread owns row er (of 64), chunks c = ec2 and ec2+4
  const int er = tid >> 2, ec2 = tid & 3;
  const float a1 = a1p[b * SS + q0 + er];
  const f16* gS = Sp + ((size_t)b * SS + q0 + er) * SS + ec2 * 8;
  const int aoff0 = er * 64 + ((ec2 ^ (er & 7)) << 3);
  const int aoff1 = er * 64 + (((ec2 + 4) ^ (er & 7)) << 3);

  // B staging map: wave w round j covers Vt rows [w*32 + j*8, +8)
  const int brow = w * 32 + (lane >> 3);           // + j*8
  const int bsw  = ((lane & 7) ^ (brow & 7)) * 8;  // swizzle const per lane
  const bf16* gB = Vt + ((size_t)b * DD + d0) * SS;
  const bf16* srcB0 = gB + (size_t)(brow + 0) * SS + bsw;
  const bf16* srcB1 = gB + (size_t)(brow + 8) * SS + bsw;
  const bf16* srcB2 = gB + (size_t)(brow + 16) * SS + bsw;
  const bf16* srcB3 = gB + (size_t)(brow + 24) * SS + bsw;

  f32x16 acc[2][2];
#pragma unroll
  for (int i = 0; i < 2; ++i)
#pragma unroll
    for (int j = 0; j < 2; ++j) acc[i][j] = (f32x16){};

  float loc = 0.f;   // this thread's share of den[er]

#define EXPWRITE(o)                                               \
  {                                                               \
    bf16x8 pb0, pb1;                                              \
    _Pragma("unroll")                                             \
    for (int u = 0; u < 8; ++u) {                                 \
      float p0 = exp2f((float)hv0[u] * a1);                       \
      float p1 = exp2f((float)hv1[u] * a1);                       \
      bf16 c0 = (bf16)p0, c1 = (bf16)p1;                          \
      pb0[u] = c0; pb1[u] = c1;                                   \
      loc += (float)c0 + (float)c1;                               \
    }                                                             \
    *(bf16x8*)&At[o][aoff0] = pb0;                                \
    *(bf16x8*)&At[o][aoff1] = pb1;                                \
  }

#define STAGEB(o, kc)                                             \
  {                                                               \
    bf16* Bo = Bt[o] + (w * 32) * 64;                             \
    gload_lds16(srcB0 + (kc), Bo);                                \
    gload_lds16(srcB1 + (kc), Bo + 8 * 64);                       \
    gload_lds16(srcB2 + (kc), Bo + 16 * 64);                      \
    gload_lds16(srcB3 + (kc), Bo + 24 * 64);                      \
  }

  // prologue: tile 0 into buffer 0, prefetch S(1)
  f16x8 hv0 = *(const f16x8*)gS;
  f16x8 hv1 = *(const f16x8*)(gS + 32);
  EXPWRITE(0)
  STAGEB(0, 0)
  hv0 = *(const f16x8*)(gS + 64);
  hv1 = *(const f16x8*)(gS + 96);
  __syncthreads();

  for (int t = 0; t < 32; ++t) {
    const int cur = t & 1, o = cur ^ 1;
    if (t < 31) {
      EXPWRITE(o)
      STAGEB(o, (t + 1) * 64)
    }
    if (t < 30) {
      hv0 = *(const f16x8*)(gS + (t + 2) * 64);
      hv1 = *(const f16x8*)(gS + (t + 2) * 64 + 32);
    }

#pragma unroll
    for (int kk = 0; kk < 2; ++kk) {
      const int slot = (wk * 2 + kk) * 2 + lh;     // 0..7
      const int ra0 = l31, ra1 = 32 + l31;
      const int rb0 = wd * 64 + l31, rb1 = wd * 64 + 32 + l31;
      bf16x8 a0 = *(const bf16x8*)&At[cur][ra0 * 64 + ((slot ^ (ra0 & 7)) << 3)];
      bf16x8 a1f = *(const bf16x8*)&At[cur][ra1 * 64 + ((slot ^ (ra1 & 7)) << 3)];
      bf16x8 b0 = *(const bf16x8*)&Bt[cur][rb0 * 64 + ((slot ^ (rb0 & 7)) << 3)];
      bf16x8 b1 = *(const bf16x8*)&Bt[cur][rb1 * 64 + ((slot ^ (rb1 & 7)) << 3)];
      acc[0][0] = __builtin_amdgcn_mfma_f32_32x32x16_bf16(a0, b0, acc[0][0], 0, 0, 0);
      acc[0][1] = __builtin_amdgcn_mfma_f32_32x32x16_bf16(a0, b1, acc[0][1], 0, 0, 0);
      acc[1][0] = __builtin_amdgcn_mfma_f32_32x32x16_bf16(a1f, b0, acc[1][0], 0, 0, 0);
      acc[1][1] = __builtin_amdgcn_mfma_f32_32x32x16_bf16(a1f, b1, acc[1][1], 0, 0, 0);
    }
    __syncthreads();
  }

  // den partials + k-half merge
  denp[tid] = loc;
  int qrow[16];
#pragma unroll
  for (int r = 0; r < 16; ++r) qrow[r] = (r & 3) + 8 * (r >> 2) + 4 * lh;

  float* Lred = (float*)&Bt[0][0];   // 64x128 f32 = 32 KB, exactly Bt
  if (wk == 1) {
#pragma unroll
    for (int i = 0; i < 2; ++i)
#pragma unroll
      for (int j = 0; j < 2; ++j)
#pragma unroll
        for (int r = 0; r < 16; ++r) {
          int row = i * 32 + qrow[r];
          Lred[row * 128 + wd * 64 + j * 32 + l31] = acc[i][j][r];
        }
  }
  __syncthreads();
  if (tid < 64) {
    float s = denp[tid * 4] + denp[tid * 4 + 1] + denp[tid * 4 + 2] + denp[tid * 4 + 3];
    dinv[tid] = 1.0f / s;
  }
  __syncthreads();
  if (wk == 0) {
    float* Ob = out + ((size_t)b * SS + q0) * DD + d0 + wd * 64;
#pragma unroll
    for (int i = 0; i < 2; ++i)
#pragma unroll
      for (int j = 0; j < 2; ++j)
#pragma unroll
        for (int r = 0; r < 16; ++r) {
          int row = i * 32 + qrow[r];
          Ob[(size_t)row * DD + j * 32 + l31] =
              (acc[i][j][r] + Lred[row * 128 + wd * 64 + j * 32 + l31]) * dinv[row];
        }
  }
#undef EXPWRITE
#undef STAGEB
}

// ---------------- fallback (round-1 kernel, zero workspace) ----------------

#define QS_STRIDE 520
#define KS_STRIDE 72
#define VT_STRIDE 18
#define PS_STRIDE 136

__device__ __forceinline__ f32x16 qk_tile(const float* __restrict__ Kb,
                                          const bf16* __restrict__ Qsl,
                                          bf16* __restrict__ KVw,
                                          int l31, int lh8, int lane) {
  f32x16 acc = {};
  for (int dc = 0; dc < DD; dc += 64) {
#pragma unroll
    for (int i = 0; i < 8; ++i) {
      int f = i * 64 + lane;
      int row = f >> 4;
      int c4 = (f & 15) * 4;
      float4 v = *(const float4*)(Kb + row * DD + dc + c4);
      bf16x4 h = { (bf16)v.x, (bf16)v.y, (bf16)v.z, (bf16)v.w };
      *(bf16x4*)&KVw[row * KS_STRIDE + c4] = h;
    }
#pragma unroll
    for (int ks = 0; ks < 4; ++ks) {
      bf16x8 a  = *(const bf16x8*)&Qsl[l31 * QS_STRIDE + dc + ks * 16 + lh8];
      bf16x8 bb = *(const bf16x8*)&KVw[l31 * KS_STRIDE + ks * 16 + lh8];
      acc = __builtin_amdgcn_mfma_f32_32x32x16_bf16(a, bb, acc, 0, 0, 0);
    }
  }
  return acc;
}

__launch_bounds__(256, 1)
__global__ void nm_attn_kernel(const float* __restrict__ Qp,
                               const float* __restrict__ Kp,
                               const float* __restrict__ Vp,
                               float* __restrict__ Op) {
  __shared__ bf16 Qs[32 * QS_STRIDE];
  __shared__ bf16 KVu[4][32 * KS_STRIDE];
  __shared__ bf16 Psl[32 * PS_STRIDE];
  __shared__ float redA[4][32];
  __shared__ float redB[4][32];
  __shared__ float a0v[32], a1v[32], idv[32];

  const int tid  = threadIdx.x;
  const int w    = tid >> 6;
  const int lane = tid & 63;
  const int l31  = lane & 31;
  const int lh8  = (lane >> 5) * 8;
  const int b    = blockIdx.y;
  const int q0   = blockIdx.x * 32;

  {
    const float* Qbase = Qp + (size_t)(b * SS + q0) * DD;
#pragma unroll
    for (int i = 0; i < 16; ++i) {
      int f = i * 256 + tid;
      int row = f >> 7;
      int c4 = (f & 127) * 4;
      float4 v = *(const float4*)(Qbase + row * DD + c4);
      bf16x4 h = { (bf16)v.x, (bf16)v.y, (bf16)v.z, (bf16)v.w };
      *(bf16x4*)&Qs[row * QS_STRIDE + c4] = h;
    }
  }
  __syncthreads();

  int qrow[16];
#pragma unroll
  for (int r = 0; r < 16; ++r) qrow[r] = (r & 3) + 8 * (r >> 2) + 4 * (lane >> 5);

  float sumv[16], sqv[16];
#pragma unroll
  for (int r = 0; r < 16; ++r) { sumv[r] = 0.f; sqv[r] = 0.f; }

  for (int kt = 0; kt < 16; ++kt) {
    const float* Kb = Kp + (size_t)(b * SS + kt * 128 + w * 32) * DD;
    f32x16 acc = qk_tile(Kb, Qs, KVu[w], l31, lh8, lane);
#pragma unroll
    for (int r = 0; r < 16; ++r) {
      float s = acc[r] * SCALE;
      sumv[r] += s;
      sqv[r]  += s * s;
    }
  }

#pragma unroll
  for (int r = 0; r < 16; ++r) {
    float v1 = sumv[r], v2 = sqv[r];
#pragma unroll
    for (int m = 16; m >= 1; m >>= 1) {
      v1 += __shfl_xor(v1, m);
      v2 += __shfl_xor(v2, m);
    }
    if (l31 == 0) { redA[w][qrow[r]] = v1; redB[w][qrow[r]] = v2; }
  }
  __syncthreads();
  if (tid < 32) {
    float s  = redA[0][tid] + redA[1][tid] + redA[2][tid] + redA[3][tid];
    float sq = redB[0][tid] + redB[1][tid] + redB[2][tid] + redB[3][tid];
    float mean = s * (1.0f / 2048.0f);
    float var = (sq - 2048.0f * mean * mean) * (1.0f / 2047.0f);
    var = fmaxf(var, 0.0f);
    float istd = 1.0f / (sqrtf(var) + 1e-6f);
    a1v[tid] = istd * LOG2E;
    a0v[tid] = -mean * istd * LOG2E;
  }
  __syncthreads();

  float a0r[16], a1r[16], den[16];
#pragma unroll
  for (int r = 0; r < 16; ++r) {
    a0r[r] = a0v[qrow[r]];
    a1r[r] = a1v[qrow[r]];
    den[r] = 0.f;
  }

  f32x16 Oa[4] = {};

  for (int kt = 0; kt < 16; ++kt) {
    const float* Kb = Kp + (size_t)(b * SS + kt * 128 + w * 32) * DD;
    f32x16 acc = qk_tile(Kb, Qs, KVu[w], l31, lh8, lane);

    __syncthreads();
#pragma unroll
    for (int r = 0; r < 16; ++r) {
      float s = acc[r] * SCALE;
      float p = exp2f(fmaf(s, a1r[r], a0r[r]));
      den[r] += p;
      Psl[qrow[r] * PS_STRIDE + w * 32 + l31] = (bf16)p;
    }
    __syncthreads();

    const float* Vb = Vp + (size_t)(b * SS + kt * 128) * DD + w * 128 + 2 * lane;
    bf16* Vts = KVu[w];
    const int d0 = 2 * lane;
    for (int ks2 = 0; ks2 < 8; ++ks2) {
      const float* Vk = Vb + ks2 * 16 * DD;
#pragma unroll
      for (int i = 0; i < 8; ++i) {
        float2 va = *(const float2*)(Vk + (2 * i) * DD);
        float2 vc = *(const float2*)(Vk + (2 * i + 1) * DD);
        bf16x2 h0 = { (bf16)va.x, (bf16)vc.x };
        bf16x2 h1 = { (bf16)va.y, (bf16)vc.y };
        *(bf16x2*)&Vts[d0 * VT_STRIDE + 2 * i] = h0;
        *(bf16x2*)&Vts[(d0 + 1) * VT_STRIDE + 2 * i] = h1;
      }
      bf16x8 aP = *(const bf16x8*)&Psl[l31 * PS_STRIDE + ks2 * 16 + lh8];
#pragma unroll
      for (int dt = 0; dt < 4; ++dt) {
        const bf16* vr = &Vts[(dt * 32 + l31) * VT_STRIDE + lh8];
        bf16x2 e0 = *(const bf16x2*)(vr + 0);
        bf16x2 e1 = *(const bf16x2*)(vr + 2);
        bf16x2 e2 = *(const bf16x2*)(vr + 4);
        bf16x2 e3 = *(const bf16x2*)(vr + 6);
        bf16x8 bV = { e0.x, e0.y, e1.x, e1.y, e2.x, e2.y, e3.x, e3.y };
        Oa[dt] = __builtin_amdgcn_mfma_f32_32x32x16_bf16(aP, bV, Oa[dt], 0, 0, 0);
      }
    }
  }

#pragma unroll
  for (int r = 0; r < 16; ++r) {
    float v1 = den[r];
#pragma unroll
    for (int m = 16; m >= 1; m >>= 1) v1 += __shfl_xor(v1, m);
    if (l31 == 0) redA[w][qrow[r]] = v1;
  }
  __syncthreads();
  if (tid < 32) {
    float t = redA[0][tid] + redA[1][tid] + redA[2][tid] + redA[3][tid];
    idv[tid] = 1.0f / t;
  }
  __syncthreads();

  float idr[16];
#pragma unroll
  for (int r = 0; r < 16; ++r) idr[r] = idv[qrow[r]];

  float* Ob = Op + (size_t)(b * SS + q0) * DD + w * 128;
#pragma unroll
  for (int dt = 0; dt < 4; ++dt) {
#pragma unroll
    for (int r = 0; r < 16; ++r) {
      Ob[qrow[r] * DD + dt * 32 + l31] = Oa[dt][r] * idr[r];
    }
  }
}

// ---------------- launcher ----------------

extern "C" void kernel_launch(void* const* d_in, const int* in_sizes, int n_in,
                              void* d_out, int out_size, void* d_ws, size_t ws_size,
                              hipStream_t stream) {
  const float* Q = (const float*)d_in[0];
  const float* K = (const float*)d_in[1];
  const float* V = (const float*)d_in[2];
  float* out = (float*)d_out;
  (void)in_sizes; (void)n_in; (void)out_size;

  const size_t E  = (size_t)BB * SS * DD;   // 4,194,304 elems / tensor
  const size_t SE = (size_t)BB * SS * SS;   // 16,777,216 score elems

  // ws layout: [Qb bf16 E][Kb bf16 E][Vt bf16 E][S f16 SE][a1 B*S f32]
  const size_t off_Kb  = E * sizeof(bf16);
  const size_t off_Vt  = off_Kb + E * sizeof(bf16);
  const size_t off_S   = off_Vt + E * sizeof(bf16);
  const size_t off_a1  = off_S + SE * sizeof(f16);
  const size_t need    = off_a1 + (size_t)BB * SS * sizeof(float);  // ~58.8 MB

  if (ws_size >= need) {
    char* ws = (char*)d_ws;
    bf16*  Qb  = (bf16*)ws;
    bf16*  Kb  = (bf16*)(ws + off_Kb);
    bf16*  Vt  = (bf16*)(ws + off_Vt);
    f16*   Sp  = (f16*)(ws + off_S);
    float* a1p = (float*)(ws + off_a1);

    prep_kernel<<<2048 + 1024, 256, 0, stream>>>(Q, K, V, Qb, Kb, Vt);
    qk_gemm_kernel<<<dim3(SS / 128, SS / 256, BB), 256, 0, stream>>>(Qb, Kb, Sp);
    stats_kernel<<<dim3(SS, BB), 256, 0, stream>>>(Sp, a1p);
    smpv_kernel<<<512, 256, 0, stream>>>(Sp, Vt, a1p, out);
  } else {
    nm_attn_kernel<<<dim3(SS / 32, BB), dim3(256, 1, 1), 0, stream>>>(Q, K, V, out);
  }
}

// Round 6
// 178.789 us; speedup vs baseline: 1.0486x; 1.0486x over previous
//
#include <hip/hip_runtime.h>

// NeuromodulatedAttention — MI355X (gfx950), round 13
//
// ALGEBRA: (1) dopamine/serotonin "mod" is a per-row constant added before the
// per-row mean/std normalization -> cancels exactly (both MLPs are dead code).
// (2) the mean subtraction is a per-row constant inside softmax -> also cancels.
// Effective:  out = softmax( S * istd_row ) @ V,
//   S = Q K^T / sqrt(512),  istd_row = 1/(std(S_row, ddof=1) + 1e-6).
//
// Round-13 delta vs round 12 (187.5us; smpv 54.7 — the 2x256 split added 2x exp
// VALU + 33MB HBM with no extra waves/CU; r10's 512-thr shape (40.8us) is the
// proven smpv optimum — all three inner-loop rearrangements lost to it):
//   * smpv_kernel: exact r10 structure + FUSED PASS-1 STATS: each thread
//     accumulates sum/sumsq over its own 32 S-chunks (the same elements it
//     exps in pass 2), 3x shfl_xor across the row's 8 threads, a1 computed
//     locally. stats_kernel + a1 buffer + one dispatch gap eliminated; pass-1
//     warms L2 for pass-2. den now accumulated from f32 p (drops 8 cvts/iter;
//     ~1e-4 rel den shift, inside the 9.8e-4 absmax budget).
//   * qk / prep / fallback: byte-identical to round 12.

#define BB 4
#define SS 2048
#define DD 512
#define SCALE 0.044194173824159216f  // 1/sqrt(512)
#define LOG2E 1.4426950408889634f

typedef __bf16 bf16;
typedef _Float16 f16;
typedef bf16 bf16x2 __attribute__((ext_vector_type(2)));
typedef bf16 bf16x4 __attribute__((ext_vector_type(4)));
typedef bf16 bf16x8 __attribute__((ext_vector_type(8)));
typedef f16  f16x8  __attribute__((ext_vector_type(8)));
typedef float f32x16 __attribute__((ext_vector_type(16)));

// async 16B/lane global->LDS; LDS dest = wave-uniform base + lane*16.
__device__ __forceinline__ void gload_lds16(const bf16* g, bf16* l) {
  __builtin_amdgcn_global_load_lds(
      (const __attribute__((address_space(1))) void*)g,
      (__attribute__((address_space(3))) void*)l, 16, 0, 0);
}

// ---------------- K1: prep = cast Q,K (bf16) + transpose V (bf16 [b][d][s]) ----

__global__ void prep_kernel(const float* __restrict__ Q, const float* __restrict__ K,
                            const float* __restrict__ V,
                            bf16* __restrict__ Qb, bf16* __restrict__ Kb,
                            bf16* __restrict__ Vt) {
  __shared__ bf16 tile[64][80];
  const int bx = blockIdx.x;
  const int t = threadIdx.x;
  if (bx < 2048) {
    // cast 8 elems of Q and K per thread
    size_t i = ((size_t)bx * 256 + t) * 8;
    float4 a0 = *(const float4*)(Q + i);
    float4 a1 = *(const float4*)(Q + i + 4);
    bf16x8 qa = { (bf16)a0.x, (bf16)a0.y, (bf16)a0.z, (bf16)a0.w,
                  (bf16)a1.x, (bf16)a1.y, (bf16)a1.z, (bf16)a1.w };
    *(bf16x8*)(Qb + i) = qa;
    float4 b0 = *(const float4*)(K + i);
    float4 b1 = *(const float4*)(K + i + 4);
    bf16x8 ka = { (bf16)b0.x, (bf16)b0.y, (bf16)b0.z, (bf16)b0.w,
                  (bf16)b1.x, (bf16)b1.y, (bf16)b1.z, (bf16)b1.w };
    *(bf16x8*)(Kb + i) = ka;
  } else {
    // V transpose, 64x64 tile
    const int tt = bx - 2048;
    const int s0 = (tt & 31) * 64, d0 = ((tt >> 5) & 7) * 64, b = tt >> 8;
    const int r16 = t >> 4;
    const int c4  = (t & 15) * 4;
#pragma unroll
    for (int i = 0; i < 4; ++i) {
      int r = i * 16 + r16;
      float4 v = *(const float4*)&V[((size_t)b * SS + s0 + r) * DD + d0 + c4];
      tile[c4 + 0][r] = (bf16)v.x;
      tile[c4 + 1][r] = (bf16)v.y;
      tile[c4 + 2][r] = (bf16)v.z;
      tile[c4 + 3][r] = (bf16)v.w;
    }
    __syncthreads();
    const int dr8 = t >> 3;
    const int sc8 = (t & 7) * 8;
#pragma unroll
    for (int i = 0; i < 2; ++i) {
      int dr = i * 32 + dr8;
      bf16x8 o = *(const bf16x8*)&tile[dr][sc8];
      *(bf16x8*)&Vt[((size_t)b * DD + d0 + dr) * SS + s0 + sc8] = o;
    }
  }
}

// ---------------- K2: QK^T GEMM -> S f16 (unchanged from round 8) ----------------
// grid (16 qt, 8 kt-pair, 4 b), 256 thr (4 waves). Each block: 128q x 256k
// (two 128x128 k-tiles sharing one staged A tile). BK=64 (8 iters).
// Wave (wq=w&1, wn=w>>1) owns the 64x64 quadrant of each 128x128 sub-tile.
// LDS rows 128B, chunk slot s of row r holds global chunk s^(r&7).

__launch_bounds__(256, 2)
__global__ void qk_gemm_kernel(const bf16* __restrict__ Qb, const bf16* __restrict__ Kb,
                               f16* __restrict__ Sp) {
  __shared__ bf16 At[128 * 64];
  __shared__ bf16 Bt[2][128 * 64];

  const int tid  = threadIdx.x;
  const int w    = tid >> 6;
  const int lane = tid & 63;
  const int l31  = lane & 31;
  const int lh   = lane >> 5;
  const int qt = blockIdx.x, kt2 = blockIdx.y, b = blockIdx.z;
  const int q0 = qt * 128, k0 = kt2 * 256;
  const int wq = w & 1, wn = w >> 1;
  const int m0 = wq * 64, n0 = wn * 64;

  const int srow = lane >> 3;          // row within 8-row staging group
  const int sg   = (lane & 7) ^ srow;  // swizzled global chunk index
  const bf16* gA = Qb + ((size_t)b * SS + q0) * DD;
  const bf16* gB = Kb + ((size_t)b * SS + k0) * DD;

  f32x16 acc[2][4];                    // [k-tile half][2*rowhalf + colhalf]
#pragma unroll
  for (int h = 0; h < 2; ++h)
#pragma unroll
    for (int u = 0; u < 4; ++u) acc[h][u] = (f32x16){};

  for (int dc = 0; dc < DD; dc += 64) {
    __syncthreads();
#pragma unroll
    for (int j = 0; j < 4; ++j) {
      int row = w * 32 + j * 8 + srow;
      gload_lds16(gA + (size_t)row * DD + dc + sg * 8, At + (w * 32 + j * 8) * 64);
      gload_lds16(gB + (size_t)row * DD + dc + sg * 8, Bt[0] + (w * 32 + j * 8) * 64);
      gload_lds16(gB + (size_t)(128 + row) * DD + dc + sg * 8,
                  Bt[1] + (w * 32 + j * 8) * 64);
    }
    __syncthreads();
#pragma unroll
    for (int kk = 0; kk < 4; ++kk) {
      int c = kk * 2 + lh;
      int ra0 = m0 + l31, ra1 = m0 + 32 + l31;
      int rb0 = n0 + l31, rb1 = n0 + 32 + l31;
      bf16x8 a0 = *(const bf16x8*)&At[ra0 * 64 + ((c ^ (ra0 & 7)) << 3)];
      bf16x8 a1 = *(const bf16x8*)&At[ra1 * 64 + ((c ^ (ra1 & 7)) << 3)];
#pragma unroll
      for (int h = 0; h < 2; ++h) {
        bf16x8 b0 = *(const bf16x8*)&Bt[h][rb0 * 64 + ((c ^ (rb0 & 7)) << 3)];
        bf16x8 b1 = *(const bf16x8*)&Bt[h][rb1 * 64 + ((c ^ (rb1 & 7)) << 3)];
        acc[h][0] = __builtin_amdgcn_mfma_f32_32x32x16_bf16(a0, b0, acc[h][0], 0, 0, 0);
        acc[h][1] = __builtin_amdgcn_mfma_f32_32x32x16_bf16(a0, b1, acc[h][1], 0, 0, 0);
        acc[h][2] = __builtin_amdgcn_mfma_f32_32x32x16_bf16(a1, b0, acc[h][2], 0, 0, 0);
        acc[h][3] = __builtin_amdgcn_mfma_f32_32x32x16_bf16(a1, b1, acc[h][3], 0, 0, 0);
      }
    }
  }

  int qrow[16];
#pragma unroll
  for (int r = 0; r < 16; ++r) qrow[r] = (r & 3) + 8 * (r >> 2) + 4 * lh;

  // epilogue: pure f16 stores (stats are computed by smpv pass-1 from S)
#pragma unroll
  for (int h = 0; h < 2; ++h) {
    f16* Sb = Sp + ((size_t)b * SS + q0) * SS + k0 + h * 128 + n0;
#pragma unroll
    for (int i = 0; i < 2; ++i) {
      const f32x16& A0 = acc[h][i * 2 + 0];
      const f32x16& A1 = acc[h][i * 2 + 1];
#pragma unroll
      for (int r = 0; r < 16; ++r) {
        f16* Sr = Sb + (size_t)(m0 + i * 32 + qrow[r]) * SS;
        Sr[l31]      = (f16)(A0[r] * SCALE);
        Sr[32 + l31] = (f16)(A1[r] * SCALE);
      }
    }
  }
}

// ---------------- K3: fused stats + softmax + PV GEMM -> out (fp32) ----------------
// grid: 256 blocks (bid: dt=bid&1, b=(bid>>1)&3, qt2=bid>>3) = 1 block/CU;
// 512 thr (8 waves: wd=w&3 d-tile, wk=w>>2 k-half). Block tile 64q x 256d,
// BK=64 (32 iters), double-buffered LDS, one __syncthreads per iter (r10
// structure, measured 40.8us).
// PASS 1 (new): thread (er=tid>>3, ec=tid&7) streams its own 32 S-chunks
// (row er, chunks ec+8t — exactly what it exps in pass 2), accumulates
// sum/sumsq, reduces across the row's 8 threads via 3x shfl_xor (same wave),
// computes a1 = log2e/(std+eps) locally. No stats dispatch, no a1 buffer.
// PASS 2: exp map thread owns (er, ec): load S f16x8 -> exp2(v*a1) -> bf16 ->
// XOR-swizzled ds_write At (same LDS image as a gload of P). den accumulated
// per-thread from f32 p; k-halves merged through LDS (Bt reused as f32
// scratch). S loads for iter+1/+2 prefetched during the MFMA phase.

__launch_bounds__(512)
__global__ void smpv_kernel(const f16* __restrict__ Sp, const bf16* __restrict__ Vt,
                            float* __restrict__ out) {
  __shared__ bf16 At[2][64 * 64];    // 16 KB
  __shared__ bf16 Bt[2][256 * 64];   // 64 KB (reused as f32[64][256] at end)
  __shared__ float denp[512];
  __shared__ float dinv[64];

  const int tid  = threadIdx.x;
  const int w    = tid >> 6;
  const int lane = tid & 63;
  const int l31  = lane & 31;
  const int lh   = lane >> 5;
  const int wd   = w & 3, wk = w >> 2;
  const int bid  = blockIdx.x;
  const int dt   = bid & 1, b = (bid >> 1) & 3, qt2 = bid >> 3;
  const int q0   = qt2 * 64, d0 = dt * 256;

  // exp staging map: thread owns row er (of 64), chunk ec (of 8, 8 f16 each)
  const int er = tid >> 3, ec = tid & 7;
  const f16* gS = Sp + ((size_t)b * SS + q0 + er) * SS + ec * 8;
  const int aoff = er * 64 + ((ec ^ (er & 7)) << 3);

  // ---- pass 1: row stats (sum/sumsq over this thread's own 32 chunks) ----
  float s1 = 0.f, s2 = 0.f;
#pragma unroll 4
  for (int t = 0; t < 32; ++t) {
    f16x8 x = *(const f16x8*)(gS + t * 64);
#pragma unroll
    for (int u = 0; u < 8; ++u) {
      float v = (float)x[u];
      s1 += v;
      s2 += v * v;
    }
  }
  s1 += __shfl_xor(s1, 1); s2 += __shfl_xor(s2, 1);
  s1 += __shfl_xor(s1, 2); s2 += __shfl_xor(s2, 2);
  s1 += __shfl_xor(s1, 4); s2 += __shfl_xor(s2, 4);
  float mean = s1 * (1.0f / 2048.0f);
  float var  = (s2 - 2048.0f * mean * mean) * (1.0f / 2047.0f);
  var = fmaxf(var, 0.0f);
  // p = exp((s-mean)*istd); per-row exp(-mean*istd) cancels in softmax.
  const float a1 = LOG2E / (sqrtf(var) + 1e-6f);

  // B staging map: wave w round j covers Vt rows [w*32+j*8, +8)
  const int brow = w * 32 + (lane >> 3);           // + j*8
  const int bsw  = ((lane & 7) ^ (brow & 7)) * 8;  // swizzle const per lane
  const bf16* gB = Vt + ((size_t)b * DD + d0) * SS;
  const bf16* srcB0 = gB + (size_t)(brow + 0) * SS + bsw;
  const bf16* srcB1 = gB + (size_t)(brow + 8) * SS + bsw;
  const bf16* srcB2 = gB + (size_t)(brow + 16) * SS + bsw;
  const bf16* srcB3 = gB + (size_t)(brow + 24) * SS + bsw;

  f32x16 acc[2][2];
#pragma unroll
  for (int i = 0; i < 2; ++i)
#pragma unroll
    for (int j = 0; j < 2; ++j) acc[i][j] = (f32x16){};

  float loc = 0.f;   // this thread's share of den[er]

#define EXPWRITE(o, h)                                            \
  {                                                               \
    bf16x8 pb;                                                    \
    _Pragma("unroll")                                             \
    for (int u = 0; u < 8; ++u) {                                 \
      float p = exp2f((float)(h)[u] * a1);                        \
      pb[u] = (bf16)p;                                            \
      loc += p;                                                   \
    }                                                             \
    *(bf16x8*)&At[o][aoff] = pb;                                  \
  }

#define STAGEB(o, kc)                                             \
  {                                                               \
    bf16* Bo = Bt[o] + (w * 32) * 64;                             \
    gload_lds16(srcB0 + (kc), Bo);                                \
    gload_lds16(srcB1 + (kc), Bo + 8 * 64);                       \
    gload_lds16(srcB2 + (kc), Bo + 16 * 64);                      \
    gload_lds16(srcB3 + (kc), Bo + 24 * 64);                      \
  }

  // prologue: stage tile 0 into buffer 0, prefetch S(1)
  f16x8 hv = *(const f16x8*)gS;
  EXPWRITE(0, hv)
  STAGEB(0, 0)
  hv = *(const f16x8*)(gS + 64);
  __syncthreads();

  for (int t = 0; t < 32; ++t) {
    const int cur = t & 1, o = cur ^ 1;
    if (t < 31) {
      EXPWRITE(o, hv)
      STAGEB(o, (t + 1) * 64)
    }
    if (t < 30) hv = *(const f16x8*)(gS + (t + 2) * 64);

#pragma unroll
    for (int kk = 0; kk < 2; ++kk) {
      const int slot = (wk * 2 + kk) * 2 + lh;     // 0..7
      const int ra0 = l31, ra1 = 32 + l31;
      const int rb0 = wd * 64 + l31, rb1 = wd * 64 + 32 + l31;
      bf16x8 a0 = *(const bf16x8*)&At[cur][ra0 * 64 + ((slot ^ (ra0 & 7)) << 3)];
      bf16x8 a1f = *(const bf16x8*)&At[cur][ra1 * 64 + ((slot ^ (ra1 & 7)) << 3)];
      bf16x8 b0 = *(const bf16x8*)&Bt[cur][rb0 * 64 + ((slot ^ (rb0 & 7)) << 3)];
      bf16x8 b1 = *(const bf16x8*)&Bt[cur][rb1 * 64 + ((slot ^ (rb1 & 7)) << 3)];
      acc[0][0] = __builtin_amdgcn_mfma_f32_32x32x16_bf16(a0, b0, acc[0][0], 0, 0, 0);
      acc[0][1] = __builtin_amdgcn_mfma_f32_32x32x16_bf16(a0, b1, acc[0][1], 0, 0, 0);
      acc[1][0] = __builtin_amdgcn_mfma_f32_32x32x16_bf16(a1f, b0, acc[1][0], 0, 0, 0);
      acc[1][1] = __builtin_amdgcn_mfma_f32_32x32x16_bf16(a1f, b1, acc[1][1], 0, 0, 0);
    }
    __syncthreads();
  }

  // den partials + k-half merge
  denp[tid] = loc;
  int qrow[16];
#pragma unroll
  for (int r = 0; r < 16; ++r) qrow[r] = (r & 3) + 8 * (r >> 2) + 4 * lh;

  float* Lred = (float*)&Bt[0][0];   // 64x256 f32 = 64 KB, exactly Bt
  if (wk == 1) {
#pragma unroll
    for (int i = 0; i < 2; ++i)
#pragma unroll
      for (int j = 0; j < 2; ++j)
#pragma unroll
        for (int r = 0; r < 16; ++r) {
          int row = i * 32 + qrow[r];
          Lred[row * 256 + wd * 64 + j * 32 + l31] = acc[i][j][r];
        }
  }
  __syncthreads();
  if (tid < 64) {
    float s = 0.f;
#pragma unroll
    for (int c = 0; c < 8; ++c) s += denp[tid * 8 + c];
    dinv[tid] = 1.0f / s;
  }
  __syncthreads();
  if (wk == 0) {
    float* Ob = out + ((size_t)b * SS + q0) * DD + d0 + wd * 64;
#pragma unroll
    for (int i = 0; i < 2; ++i)
#pragma unroll
      for (int j = 0; j < 2; ++j)
#pragma unroll
        for (int r = 0; r < 16; ++r) {
          int row = i * 32 + qrow[r];
          Ob[(size_t)row * DD + j * 32 + l31] =
              (acc[i][j][r] + Lred[row * 256 + wd * 64 + j * 32 + l31]) * dinv[row];
        }
  }
#undef EXPWRITE
#undef STAGEB
}

// ---------------- fallback (round-1 kernel, zero workspace) ----------------

#define QS_STRIDE 520
#define KS_STRIDE 72
#define VT_STRIDE 18
#define PS_STRIDE 136

__device__ __forceinline__ f32x16 qk_tile(const float* __restrict__ Kb,
                                          const bf16* __restrict__ Qsl,
                                          bf16* __restrict__ KVw,
                                          int l31, int lh8, int lane) {
  f32x16 acc = {};
  for (int dc = 0; dc < DD; dc += 64) {
#pragma unroll
    for (int i = 0; i < 8; ++i) {
      int f = i * 64 + lane;
      int row = f >> 4;
      int c4 = (f & 15) * 4;
      float4 v = *(const float4*)(Kb + row * DD + dc + c4);
      bf16x4 h = { (bf16)v.x, (bf16)v.y, (bf16)v.z, (bf16)v.w };
      *(bf16x4*)&KVw[row * KS_STRIDE + c4] = h;
    }
#pragma unroll
    for (int ks = 0; ks < 4; ++ks) {
      bf16x8 a  = *(const bf16x8*)&Qsl[l31 * QS_STRIDE + dc + ks * 16 + lh8];
      bf16x8 bb = *(const bf16x8*)&KVw[l31 * KS_STRIDE + ks * 16 + lh8];
      acc = __builtin_amdgcn_mfma_f32_32x32x16_bf16(a, bb, acc, 0, 0, 0);
    }
  }
  return acc;
}

__launch_bounds__(256, 1)
__global__ void nm_attn_kernel(const float* __restrict__ Qp,
                               const float* __restrict__ Kp,
                               const float* __restrict__ Vp,
                               float* __restrict__ Op) {
  __shared__ bf16 Qs[32 * QS_STRIDE];
  __shared__ bf16 KVu[4][32 * KS_STRIDE];
  __shared__ bf16 Psl[32 * PS_STRIDE];
  __shared__ float redA[4][32];
  __shared__ float redB[4][32];
  __shared__ float a0v[32], a1v[32], idv[32];

  const int tid  = threadIdx.x;
  const int w    = tid >> 6;
  const int lane = tid & 63;
  const int l31  = lane & 31;
  const int lh8  = (lane >> 5) * 8;
  const int b    = blockIdx.y;
  const int q0   = blockIdx.x * 32;

  {
    const float* Qbase = Qp + (size_t)(b * SS + q0) * DD;
#pragma unroll
    for (int i = 0; i < 16; ++i) {
      int f = i * 256 + tid;
      int row = f >> 7;
      int c4 = (f & 127) * 4;
      float4 v = *(const float4*)(Qbase + row * DD + c4);
      bf16x4 h = { (bf16)v.x, (bf16)v.y, (bf16)v.z, (bf16)v.w };
      *(bf16x4*)&Qs[row * QS_STRIDE + c4] = h;
    }
  }
  __syncthreads();

  int qrow[16];
#pragma unroll
  for (int r = 0; r < 16; ++r) qrow[r] = (r & 3) + 8 * (r >> 2) + 4 * (lane >> 5);

  float sumv[16], sqv[16];
#pragma unroll
  for (int r = 0; r < 16; ++r) { sumv[r] = 0.f; sqv[r] = 0.f; }

  for (int kt = 0; kt < 16; ++kt) {
    const float* Kb = Kp + (size_t)(b * SS + kt * 128 + w * 32) * DD;
    f32x16 acc = qk_tile(Kb, Qs, KVu[w], l31, lh8, lane);
#pragma unroll
    for (int r = 0; r < 16; ++r) {
      float s = acc[r] * SCALE;
      sumv[r] += s;
      sqv[r]  += s * s;
    }
  }

#pragma unroll
  for (int r = 0; r < 16; ++r) {
    float v1 = sumv[r], v2 = sqv[r];
#pragma unroll
    for (int m = 16; m >= 1; m >>= 1) {
      v1 += __shfl_xor(v1, m);
      v2 += __shfl_xor(v2, m);
    }
    if (l31 == 0) { redA[w][qrow[r]] = v1; redB[w][qrow[r]] = v2; }
  }
  __syncthreads();
  if (tid < 32) {
    float s  = redA[0][tid] + redA[1][tid] + redA[2][tid] + redA[3][tid];
    float sq = redB[0][tid] + redB[1][tid] + redB[2][tid] + redB[3][tid];
    float mean = s * (1.0f / 2048.0f);
    float var = (sq - 2048.0f * mean * mean) * (1.0f / 2047.0f);
    var = fmaxf(var, 0.0f);
    float istd = 1.0f / (sqrtf(var) + 1e-6f);
    a1v[tid] = istd * LOG2E;
    a0v[tid] = -mean * istd * LOG2E;
  }
  __syncthreads();

  float a0r[16], a1r[16], den[16];
#pragma unroll
  for (int r = 0; r < 16; ++r) {
    a0r[r] = a0v[qrow[r]];
    a1r[r] = a1v[qrow[r]];
    den[r] = 0.f;
  }

  f32x16 Oa[4] = {};

  for (int kt = 0; kt < 16; ++kt) {
    const float* Kb = Kp + (size_t)(b * SS + kt * 128 + w * 32) * DD;
    f32x16 acc = qk_tile(Kb, Qs, KVu[w], l31, lh8, lane);

    __syncthreads();
#pragma unroll
    for (int r = 0; r < 16; ++r) {
      float s = acc[r] * SCALE;
      float p = exp2f(fmaf(s, a1r[r], a0r[r]));
      den[r] += p;
      Psl[qrow[r] * PS_STRIDE + w * 32 + l31] = (bf16)p;
    }
    __syncthreads();

    const float* Vb = Vp + (size_t)(b * SS + kt * 128) * DD + w * 128 + 2 * lane;
    bf16* Vts = KVu[w];
    const int d0 = 2 * lane;
    for (int ks2 = 0; ks2 < 8; ++ks2) {
      const float* Vk = Vb + ks2 * 16 * DD;
#pragma unroll
      for (int i = 0; i < 8; ++i) {
        float2 va = *(const float2*)(Vk + (2 * i) * DD);
        float2 vc = *(const float2*)(Vk + (2 * i + 1) * DD);
        bf16x2 h0 = { (bf16)va.x, (bf16)vc.x };
        bf16x2 h1 = { (bf16)va.y, (bf16)vc.y };
        *(bf16x2*)&Vts[d0 * VT_STRIDE + 2 * i] = h0;
        *(bf16x2*)&Vts[(d0 + 1) * VT_STRIDE + 2 * i] = h1;
      }
      bf16x8 aP = *(const bf16x8*)&Psl[l31 * PS_STRIDE + ks2 * 16 + lh8];
#pragma unroll
      for (int dt = 0; dt < 4; ++dt) {
        const bf16* vr = &Vts[(dt * 32 + l31) * VT_STRIDE + lh8];
        bf16x2 e0 = *(const bf16x2*)(vr + 0);
        bf16x2 e1 = *(const bf16x2*)(vr + 2);
        bf16x2 e2 = *(const bf16x2*)(vr + 4);
        bf16x2 e3 = *(const bf16x2*)(vr + 6);
        bf16x8 bV = { e0.x, e0.y, e1.x, e1.y, e2.x, e2.y, e3.x, e3.y };
        Oa[dt] = __builtin_amdgcn_mfma_f32_32x32x16_bf16(aP, bV, Oa[dt], 0, 0, 0);
      }
    }
  }

#pragma unroll
  for (int r = 0; r < 16; ++r) {
    float v1 = den[r];
#pragma unroll
    for (int m = 16; m >= 1; m >>= 1) v1 += __shfl_xor(v1, m);
    if (l31 == 0) redA[w][qrow[r]] = v1;
  }
  __syncthreads();
  if (tid < 32) {
    float t = redA[0][tid] + redA[1][tid] + redA[2][tid] + redA[3][tid];
    idv[tid] = 1.0f / t;
  }
  __syncthreads();

  float idr[16];
#pragma unroll
  for (int r = 0; r < 16; ++r) idr[r] = idv[qrow[r]];

  float* Ob = Op + (size_t)(b * SS + q0) * DD + w * 128;
#pragma unroll
  for (int dt = 0; dt < 4; ++dt) {
#pragma unroll
    for (int r = 0; r < 16; ++r) {
      Ob[qrow[r] * DD + dt * 32 + l31] = Oa[dt][r] * idr[r];
    }
  }
}

// ---------------- launcher ----------------

extern "C" void kernel_launch(void* const* d_in, const int* in_sizes, int n_in,
                              void* d_out, int out_size, void* d_ws, size_t ws_size,
                              hipStream_t stream) {
  const float* Q = (const float*)d_in[0];
  const float* K = (const float*)d_in[1];
  const float* V = (const float*)d_in[2];
  float* out = (float*)d_out;
  (void)in_sizes; (void)n_in; (void)out_size;

  const size_t E  = (size_t)BB * SS * DD;   // 4,194,304 elems / tensor
  const size_t SE = (size_t)BB * SS * SS;   // 16,777,216 score elems

  // ws layout: [Qb bf16 E][Kb bf16 E][Vt bf16 E][S f16 SE]
  const size_t off_Kb  = E * sizeof(bf16);
  const size_t off_Vt  = off_Kb + E * sizeof(bf16);
  const size_t off_S   = off_Vt + E * sizeof(bf16);
  const size_t need    = off_S + SE * sizeof(f16);  // ~58.7 MB

  if (ws_size >= need) {
    char* ws = (char*)d_ws;
    bf16*  Qb  = (bf16*)ws;
    bf16*  Kb  = (bf16*)(ws + off_Kb);
    bf16*  Vt  = (bf16*)(ws + off_Vt);
    f16*   Sp  = (f16*)(ws + off_S);

    prep_kernel<<<2048 + 1024, 256, 0, stream>>>(Q, K, V, Qb, Kb, Vt);
    qk_gemm_kernel<<<dim3(SS / 128, SS / 256, BB), 256, 0, stream>>>(Qb, Kb, Sp);
    smpv_kernel<<<256, 512, 0, stream>>>(Sp, Vt, out);
  } else {
    nm_attn_kernel<<<dim3(SS / 32, BB), dim3(256, 1, 1), 0, stream>>>(Q, K, V, out);
  }
}